// Round 16
// baseline (351.199 us; speedup 1.0000x reference)
//
#include <hip/hip_runtime.h>
#include <hip/hip_bf16.h>

// Problem constants (B=2, H=W=112, C=256, NHEAD=8, STRIP=7)
#define M_ROWS 25088
#define CDIM   256
#define QKVD   768
#define LWIN   784
#define NWINH  256   // 32 windows * 8 heads

typedef __attribute__((ext_vector_type(8))) short short8v;
typedef __attribute__((ext_vector_type(4))) float floatx4;

// scale * log2(e) = (1/sqrt(32)) * 1.4426950408889634
#define CEQ 0.2550660106245232f

static __device__ __forceinline__ unsigned short f2bf(float f) {
    unsigned int x = __float_as_uint(f);
    x += 0x7fffu + ((x >> 16) & 1u);
    return (unsigned short)(x >> 16);
}
static __device__ __forceinline__ unsigned int cvt_pk_bf16(float a, float b) {
    unsigned int r;
    asm("v_cvt_pk_bf16_f32 %0, %1, %2" : "=v"(r) : "v"(a), "v"(b));
    return r;  // lo16 = bf16(a), hi16 = bf16(b)
}
static __device__ __forceinline__ void gld_lds16(const unsigned short* g,
                                                 unsigned short* l) {
    __builtin_amdgcn_global_load_lds(
        (const __attribute__((address_space(1))) unsigned int*)g,
        (__attribute__((address_space(3))) unsigned int*)l, 16, 0, 0);
}

// ---------------------------------------------------------------------------
// Kernel 0: fp32 -> bf16 pack, all three tensors in ONE launch. [R11 verbatim
// — two fusion attempts (R12 reg-stage, R15 swizzled gld_lds) both regressed]
// ---------------------------------------------------------------------------
#define N8_TOTAL ((M_ROWS * CDIM + QKVD * CDIM + CDIM * CDIM) / 8)

__global__ __launch_bounds__(256) void k_f2bf3(
    const float* __restrict__ s0,   // x       (M_ROWS*CDIM)
    const float* __restrict__ s1,   // qkv_w   (QKVD*CDIM)
    const float* __restrict__ s2,   // proj_w  (CDIM*CDIM)
    unsigned short* __restrict__ d0,
    unsigned short* __restrict__ d1,
    unsigned short* __restrict__ d2)
{
    const int n80 = (M_ROWS * CDIM) / 8;
    const int n81 = (QKVD * CDIM) / 8;
    for (int i = blockIdx.x * 256 + threadIdx.x; i < N8_TOTAL;
         i += gridDim.x * 256) {
        const float4* s4;
        uint4* d4;
        int j = i;
        if (j < n80)            { s4 = (const float4*)s0; d4 = (uint4*)d0; }
        else if ((j -= n80) < n81) { s4 = (const float4*)s1; d4 = (uint4*)d1; }
        else                    { j -= n81; s4 = (const float4*)s2; d4 = (uint4*)d2; }
        float4 a = s4[2 * j], b = s4[2 * j + 1];
        uint4 o;
        o.x = cvt_pk_bf16(a.x, a.y);
        o.y = cvt_pk_bf16(a.z, a.w);
        o.z = cvt_pk_bf16(b.x, b.y);
        o.w = cvt_pk_bf16(b.z, b.w);
        d4[j] = o;
    }
}

// ---------------------------------------------------------------------------
// Kernel 1/3: C(M,N) = A(M,256) @ B(N,256)^T [+ bias], bf16 MFMA.
// [R11 staging/compute verbatim] + T1 bijective XCD swizzle: 1D grid
// (nwg % 8 == 0), swz = (lin&7)*(nwg/8) + (lin>>3) -> each XCD covers
// contiguous row-panels across all col-tiles, so A-panel re-reads L2-hit.
// ---------------------------------------------------------------------------
template <typename OUT_T, bool BIAS, bool SCALEQ>
__global__ __launch_bounds__(256, 2) void k_gemm_mfma(
    const unsigned short* __restrict__ A,   // (M, 256) bf16
    const unsigned short* __restrict__ B,   // (N, 256) bf16
    const float* __restrict__ bias,         // (N) or nullptr
    OUT_T* __restrict__ Y, int N, int nbx)  // (M, N); nbx = N/128
{
    __shared__ __attribute__((aligned(16))) unsigned short As[128 * 64];
    __shared__ __attribute__((aligned(16))) unsigned short Bs[128 * 64];
    const int t = threadIdx.x;
    const int lane = t & 63, wv = t >> 6;
    const int lq = lane & 15, g = lane >> 4;
    const int wm = wv >> 1, wn = wv & 1;
    // T1 XCD swizzle (bijective: gridDim.x % 8 == 0)
    const int lin = blockIdx.x;
    const int swz = (lin & 7) * (gridDim.x >> 3) + (lin >> 3);
    const int R0 = (swz / nbx) * 128, C0 = (swz % nbx) * 128;
    const int lrow = t >> 3, lch = (t & 7) * 8;

    floatx4 acc[4][4];
#pragma unroll
    for (int i = 0; i < 4; ++i)
#pragma unroll
        for (int j = 0; j < 4; ++j) acc[i][j] = (floatx4){0.f, 0.f, 0.f, 0.f};

    for (int kc = 0; kc < 256; kc += 64) {
#pragma unroll
        for (int i = 0; i < 4; ++i) {
            gld_lds16(A + (size_t)(R0 + i * 32 + lrow) * 256 + kc + lch,
                      As + (i * 32 + wv * 8) * 64);
            gld_lds16(B + (size_t)(C0 + i * 32 + lrow) * 256 + kc + lch,
                      Bs + (i * 32 + wv * 8) * 64);
        }
        __syncthreads();
#pragma unroll
        for (int kk = 0; kk < 64; kk += 32) {
            short8v af[4], bf[4];
#pragma unroll
            for (int mi = 0; mi < 4; ++mi)
                af[mi] = *(const short8v*)(As + (wm * 64 + mi * 16 + lq) * 64 +
                                           kk + g * 8);
#pragma unroll
            for (int ni = 0; ni < 4; ++ni)
                bf[ni] = *(const short8v*)(Bs + (wn * 64 + ni * 16 + lq) * 64 +
                                           kk + g * 8);
#pragma unroll
            for (int mi = 0; mi < 4; ++mi)
#pragma unroll
                for (int ni = 0; ni < 4; ++ni)
                    acc[mi][ni] = __builtin_amdgcn_mfma_f32_16x16x32_bf16(
                        af[mi], bf[ni], acc[mi][ni], 0, 0, 0);
        }
        __syncthreads();
    }

#pragma unroll
    for (int mi = 0; mi < 4; ++mi) {
        const size_t rb = (size_t)R0 + wm * 64 + mi * 16 + g * 4;
#pragma unroll
        for (int ni = 0; ni < 4; ++ni) {
            const int col = C0 + wn * 64 + ni * 16 + lq;
            float bv = 0.f;
            if constexpr (BIAS) bv = bias[col];
#pragma unroll
            for (int r = 0; r < 4; ++r) {
                float val = acc[mi][ni][r];
                if constexpr (SCALEQ) { if (col < 256) val *= CEQ; }
                val += bv;
                if constexpr (sizeof(OUT_T) == 2)
                    Y[(rb + r) * N + col] = (OUT_T)f2bf(val);
                else
                    Y[(rb + r) * N + col] = (OUT_T)val;
            }
        }
    }
}

// ---------------------------------------------------------------------------
// Kernel 2: MFMA attention — R11 structure (verified 45.2us) + u-loop
// UNROLL 2: consecutive u-iterations are independent (separate kf/v/pw
// chains); unrolling lets the scheduler overlap u and u+1 to fill the
// ~50% issue-stall. VGPR budget: ~116 live < 128 cap at 4 waves/SIMD.
// Register-P via permuted k-order (pos 8g+j <-> token (j>=4?16:0)+4g+(j&3));
// V staged with matching permutation. 16 waves, 1 block/CU.
// ---------------------------------------------------------------------------
#define KPITCH 36
#define VPITCH 404                         // u32 words per d-row
#define KS_SZ  (LWIN * KPITCH)             // 28224 shorts = 56448 B
#define ATTN_LDS (KS_SZ * 2 + 32 * VPITCH * 4)   // 108160 bytes

__global__ __launch_bounds__(1024, 1) void k_attn_mfma(
    const unsigned short* __restrict__ qkv,   // (25088, 768) bf16
    unsigned short* __restrict__ ao)          // (25088, 256) bf16
{
    extern __shared__ unsigned short sm[];
    unsigned short* Ks = sm;                           // [784][36]
    unsigned int*   Vt = (unsigned int*)(sm + KS_SZ);  // [32][404]
    const int t = threadIdx.x;
    const int lane = t & 63, wave = t >> 6;
    const int lq = lane & 15, g = lane >> 4;
    const int h = blockIdx.x & 7, w = blockIdx.x >> 3;
    const size_t rowbase = (size_t)w * LWIN;
    const unsigned short* base = qkv + rowbase * QKVD;

    // ---- stage K: [784][36] ----
    for (int idx = t; idx < LWIN * 4; idx += 1024) {
        const int row = idx >> 2, c = idx & 3;
        uint4 kv = *(const uint4*)(base + (size_t)row * QKVD + 256 + h * 32 + c * 8);
        *(uint4*)(Ks + row * KPITCH + c * 8) = kv;
    }
    // ---- stage V: permuted-position packed token-pairs ----
    {
        const int c = t >> 8;          // d-octet 0..3
        const int p0 = t & 255;
        for (int tp = p0; tp < 392; tp += 256) {
            const int u = tp >> 4, tpp = tp & 15;
            const int a = tpp >> 3, gg = (tpp >> 1) & 3, rp = tpp & 1;
            const int wrd = u * 16 + gg * 4 + a * 2 + rp;
            union { uint4 u4; unsigned short s[8]; } x0, x1;
            x0.u4 = *(const uint4*)(base + (size_t)(2 * tp) * QKVD + 512 + h * 32 + c * 8);
            x1.u4 = *(const uint4*)(base + (size_t)(2 * tp + 1) * QKVD + 512 + h * 32 + c * 8);
#pragma unroll
            for (int j = 0; j < 8; ++j)
                Vt[(c * 8 + j) * VPITCH + wrd] =
                    (unsigned int)x0.s[j] | ((unsigned int)x1.s[j] << 16);
        }
    }
    // zero block-24's a=1 words (positions for the missing s=49 tile)
    for (int idx = t; idx < 32 * 8; idx += 1024) {
        const int d = idx >> 3, q = idx & 7;
        Vt[d * VPITCH + 384 + (q >> 1) * 4 + 2 + (q & 1)] = 0;
    }
    __syncthreads();

    // ---- per-wave q-tiles: wave 0 -> {0..3}, wave w -> {3w+1..3w+3} ----
    const int ntile = (wave == 0) ? 4 : 3;
    const int tbase = (wave == 0) ? 0 : (3 * wave + 1);

    short8v qf[4];
#pragma unroll
    for (int n = 0; n < 4; ++n)
        if (n < ntile)
            qf[n] = *(const short8v*)(base +
                    (size_t)((tbase + n) * 16 + lq) * QKVD + h * 32 + g * 8);

    floatx4 oa[4][2];
#pragma unroll
    for (int n = 0; n < 4; ++n) {
        oa[n][0] = (floatx4){0.f, 0.f, 0.f, 0.f};
        oa[n][1] = (floatx4){0.f, 0.f, 0.f, 0.f};
    }
    float lsum[4] = {0.f, 0.f, 0.f, 0.f};

#pragma unroll 2
    for (int u = 0; u < 25; ++u) {
        unsigned int pw[4][4];
        __builtin_amdgcn_s_setprio(1);
        {   // s = 2u
            short8v kf = *(const short8v*)(Ks + (size_t)(2 * u * 16 + lq) * KPITCH + g * 8);
#pragma unroll
            for (int n = 0; n < 4; ++n) if (n < ntile) {
                floatx4 st = __builtin_amdgcn_mfma_f32_16x16x32_bf16(
                    kf, qf[n], (floatx4){0.f, 0.f, 0.f, 0.f}, 0, 0, 0);
                float p0 = __builtin_amdgcn_exp2f(st[0]);
                float p1 = __builtin_amdgcn_exp2f(st[1]);
                float p2 = __builtin_amdgcn_exp2f(st[2]);
                float p3 = __builtin_amdgcn_exp2f(st[3]);
                lsum[n] += (p0 + p1) + (p2 + p3);
                pw[n][0] = cvt_pk_bf16(p0, p1);
                pw[n][1] = cvt_pk_bf16(p2, p3);
            }
        }
        if (u < 24) {   // s = 2u+1
            short8v kf = *(const short8v*)(Ks + (size_t)((2 * u + 1) * 16 + lq) * KPITCH + g * 8);
#pragma unroll
            for (int n = 0; n < 4; ++n) if (n < ntile) {
                floatx4 st = __builtin_amdgcn_mfma_f32_16x16x32_bf16(
                    kf, qf[n], (floatx4){0.f, 0.f, 0.f, 0.f}, 0, 0, 0);
                float p0 = __builtin_amdgcn_exp2f(st[0]);
                float p1 = __builtin_amdgcn_exp2f(st[1]);
                float p2 = __builtin_amdgcn_exp2f(st[2]);
                float p3 = __builtin_amdgcn_exp2f(st[3]);
                lsum[n] += (p0 + p1) + (p2 + p3);
                pw[n][2] = cvt_pk_bf16(p0, p1);
                pw[n][3] = cvt_pk_bf16(p2, p3);
            }
        } else {
#pragma unroll
            for (int n = 0; n < 4; ++n) if (n < ntile) {
                pw[n][2] = 0u; pw[n][3] = 0u;
            }
        }
        // ---- PV: A-frag = own pw words (permuted k-order), B = V from LDS ----
        const unsigned short* vrow0 = (const unsigned short*)Vt;
        short8v v0 = *(const short8v*)(vrow0 + (size_t)lq * (VPITCH * 2) + u * 32 + g * 8);
        short8v v1 = *(const short8v*)(vrow0 + (size_t)(lq + 16) * (VPITCH * 2) + u * 32 + g * 8);
#pragma unroll
        for (int n = 0; n < 4; ++n) if (n < ntile) {
            union { unsigned int wd[4]; short8v v; } pu;
            pu.wd[0] = pw[n][0]; pu.wd[1] = pw[n][1];
            pu.wd[2] = pw[n][2]; pu.wd[3] = pw[n][3];
            oa[n][0] = __builtin_amdgcn_mfma_f32_16x16x32_bf16(pu.v, v0, oa[n][0], 0, 0, 0);
            oa[n][1] = __builtin_amdgcn_mfma_f32_16x16x32_bf16(pu.v, v1, oa[n][1], 0, 0, 0);
        }
        __builtin_amdgcn_s_setprio(0);
    }

    // ---- normalize + store ----
#pragma unroll
    for (int n = 0; n < 4; ++n) if (n < ntile) {
        float l = lsum[n];
        l += __shfl_xor(l, 16);
        l += __shfl_xor(l, 32);
        float inv = 1.f / l;
        const size_t orow0 = rowbase + (size_t)(tbase + n) * 16;
#pragma unroll
        for (int r = 0; r < 4; ++r) {
            float ir = __shfl(inv, (lane & 48) | (g * 4 + r));
            size_t ob = (orow0 + g * 4 + r) * CDIM + h * 32;
            ao[ob + lq]      = f2bf(oa[n][0][r] * ir);
            ao[ob + 16 + lq] = f2bf(oa[n][1][r] * ir);
        }
    }
}

extern "C" void kernel_launch(void* const* d_in, const int* in_sizes, int n_in,
                              void* d_out, int out_size, void* d_ws, size_t ws_size,
                              hipStream_t stream) {
    const float* x      = (const float*)d_in[0];
    const float* qkv_w  = (const float*)d_in[1];
    const float* proj_w = (const float*)d_in[2];
    const float* proj_b = (const float*)d_in[3];
    float* out = (float*)d_out;

    unsigned short* qkvb = (unsigned short*)d_ws;
    unsigned short* xb   = qkvb + (size_t)M_ROWS * QKVD;
    unsigned short* aob  = xb;  // alias: xb dead once GEMM1 completes
    unsigned short* wqb  = xb + (size_t)M_ROWS * CDIM;
    unsigned short* wpb  = wqb + (size_t)QKVD * CDIM;

    hipFuncSetAttribute((const void*)k_attn_mfma,
                        hipFuncAttributeMaxDynamicSharedMemorySize, ATTN_LDS);

    k_f2bf3<<<2048, 256, 0, stream>>>(x, qkv_w, proj_w, xb, wqb, wpb);

    // GEMM1: grid = 6 * 196 = 1176 (8 | 1176)
    k_gemm_mfma<unsigned short, false, true>
        <<<(QKVD / 128) * (M_ROWS / 128), 256, 0, stream>>>(
            xb, wqb, nullptr, qkvb, QKVD, QKVD / 128);

    k_attn_mfma<<<dim3(NWINH), 1024, ATTN_LDS, stream>>>(qkvb, aob);

    // GEMM2: grid = 2 * 196 = 392 (8 | 392)
    k_gemm_mfma<float, true, false>
        <<<(CDIM / 128) * (M_ROWS / 128), 256, 0, stream>>>(
            aob, wpb, proj_b, out, CDIM, CDIM / 128);
}

// Round 17
// 80.910 us; speedup vs baseline: 4.3406x; 4.3406x over previous
//
#include <hip/hip_runtime.h>
#include <hip/hip_bf16.h>

// Problem constants (B=2, H=W=112, C=256, NHEAD=8, STRIP=7)
#define M_ROWS 25088
#define CDIM   256
#define QKVD   768
#define LWIN   784
#define NWINH  256   // 32 windows * 8 heads

typedef __attribute__((ext_vector_type(8))) short short8v;
typedef __attribute__((ext_vector_type(4))) float floatx4;

// scale * log2(e) = (1/sqrt(32)) * 1.4426950408889634
#define CEQ 0.2550660106245232f

static __device__ __forceinline__ unsigned short f2bf(float f) {
    unsigned int x = __float_as_uint(f);
    x += 0x7fffu + ((x >> 16) & 1u);
    return (unsigned short)(x >> 16);
}
static __device__ __forceinline__ unsigned int cvt_pk_bf16(float a, float b) {
    unsigned int r;
    asm("v_cvt_pk_bf16_f32 %0, %1, %2" : "=v"(r) : "v"(a), "v"(b));
    return r;  // lo16 = bf16(a), hi16 = bf16(b)
}
static __device__ __forceinline__ void gld_lds16(const unsigned short* g,
                                                 unsigned short* l) {
    __builtin_amdgcn_global_load_lds(
        (const __attribute__((address_space(1))) unsigned int*)g,
        (__attribute__((address_space(3))) unsigned int*)l, 16, 0, 0);
}

// ---------------------------------------------------------------------------
// Kernel 0: fp32 -> bf16 pack, all three tensors in ONE launch. [R11 verbatim]
// ---------------------------------------------------------------------------
#define N8_TOTAL ((M_ROWS * CDIM + QKVD * CDIM + CDIM * CDIM) / 8)

__global__ __launch_bounds__(256) void k_f2bf3(
    const float* __restrict__ s0,   // x       (M_ROWS*CDIM)
    const float* __restrict__ s1,   // qkv_w   (QKVD*CDIM)
    const float* __restrict__ s2,   // proj_w  (CDIM*CDIM)
    unsigned short* __restrict__ d0,
    unsigned short* __restrict__ d1,
    unsigned short* __restrict__ d2)
{
    const int n80 = (M_ROWS * CDIM) / 8;
    const int n81 = (QKVD * CDIM) / 8;
    for (int i = blockIdx.x * 256 + threadIdx.x; i < N8_TOTAL;
         i += gridDim.x * 256) {
        const float4* s4;
        uint4* d4;
        int j = i;
        if (j < n80)            { s4 = (const float4*)s0; d4 = (uint4*)d0; }
        else if ((j -= n80) < n81) { s4 = (const float4*)s1; d4 = (uint4*)d1; }
        else                    { j -= n81; s4 = (const float4*)s2; d4 = (uint4*)d2; }
        float4 a = s4[2 * j], b = s4[2 * j + 1];
        uint4 o;
        o.x = cvt_pk_bf16(a.x, a.y);
        o.y = cvt_pk_bf16(a.z, a.w);
        o.z = cvt_pk_bf16(b.x, b.y);
        o.w = cvt_pk_bf16(b.z, b.w);
        d4[j] = o;
    }
}

// ---------------------------------------------------------------------------
// Kernel 1/3: C(M,N) = A(M,256) @ B(N,256)^T [+ bias], bf16 MFMA.
// [R11 staging/compute verbatim] + T1 bijective XCD swizzle (isolated test;
// correctness-proven in R16): 1D grid (nwg % 8 == 0),
// swz = (lin&7)*(nwg/8) + (lin>>3) -> each XCD covers contiguous row-panels
// across all col-tiles, so A-panel re-reads stay in one L2.
// ---------------------------------------------------------------------------
template <typename OUT_T, bool BIAS, bool SCALEQ>
__global__ __launch_bounds__(256, 2) void k_gemm_mfma(
    const unsigned short* __restrict__ A,   // (M, 256) bf16
    const unsigned short* __restrict__ B,   // (N, 256) bf16
    const float* __restrict__ bias,         // (N) or nullptr
    OUT_T* __restrict__ Y, int N, int nbx)  // (M, N); nbx = N/128
{
    __shared__ __attribute__((aligned(16))) unsigned short As[128 * 64];
    __shared__ __attribute__((aligned(16))) unsigned short Bs[128 * 64];
    const int t = threadIdx.x;
    const int lane = t & 63, wv = t >> 6;
    const int lq = lane & 15, g = lane >> 4;
    const int wm = wv >> 1, wn = wv & 1;
    const int lin = blockIdx.x;
    const int swz = (lin & 7) * (gridDim.x >> 3) + (lin >> 3);
    const int R0 = (swz / nbx) * 128, C0 = (swz % nbx) * 128;
    const int lrow = t >> 3, lch = (t & 7) * 8;

    floatx4 acc[4][4];
#pragma unroll
    for (int i = 0; i < 4; ++i)
#pragma unroll
        for (int j = 0; j < 4; ++j) acc[i][j] = (floatx4){0.f, 0.f, 0.f, 0.f};

    for (int kc = 0; kc < 256; kc += 64) {
#pragma unroll
        for (int i = 0; i < 4; ++i) {
            gld_lds16(A + (size_t)(R0 + i * 32 + lrow) * 256 + kc + lch,
                      As + (i * 32 + wv * 8) * 64);
            gld_lds16(B + (size_t)(C0 + i * 32 + lrow) * 256 + kc + lch,
                      Bs + (i * 32 + wv * 8) * 64);
        }
        __syncthreads();
#pragma unroll
        for (int kk = 0; kk < 64; kk += 32) {
            short8v af[4], bf[4];
#pragma unroll
            for (int mi = 0; mi < 4; ++mi)
                af[mi] = *(const short8v*)(As + (wm * 64 + mi * 16 + lq) * 64 +
                                           kk + g * 8);
#pragma unroll
            for (int ni = 0; ni < 4; ++ni)
                bf[ni] = *(const short8v*)(Bs + (wn * 64 + ni * 16 + lq) * 64 +
                                           kk + g * 8);
#pragma unroll
            for (int mi = 0; mi < 4; ++mi)
#pragma unroll
                for (int ni = 0; ni < 4; ++ni)
                    acc[mi][ni] = __builtin_amdgcn_mfma_f32_16x16x32_bf16(
                        af[mi], bf[ni], acc[mi][ni], 0, 0, 0);
        }
        __syncthreads();
    }

#pragma unroll
    for (int mi = 0; mi < 4; ++mi) {
        const size_t rb = (size_t)R0 + wm * 64 + mi * 16 + g * 4;
#pragma unroll
        for (int ni = 0; ni < 4; ++ni) {
            const int col = C0 + wn * 64 + ni * 16 + lq;
            float bv = 0.f;
            if constexpr (BIAS) bv = bias[col];
#pragma unroll
            for (int r = 0; r < 4; ++r) {
                float val = acc[mi][ni][r];
                if constexpr (SCALEQ) { if (col < 256) val *= CEQ; }
                val += bv;
                if constexpr (sizeof(OUT_T) == 2)
                    Y[(rb + r) * N + col] = (OUT_T)f2bf(val);
                else
                    Y[(rb + r) * N + col] = (OUT_T)val;
            }
        }
    }
}

// ---------------------------------------------------------------------------
// Kernel 2: MFMA attention — R11 VERBATIM (verified 45.2us; 7 structural
// alternatives all regressed, incl. R16's unroll-2 spill catastrophe).
// Register-P via permuted k-order (pos 8g+j <-> token (j>=4?16:0)+4g+(j&3));
// V staged with matching permutation. K: [784][36] shorts. V: [32][404]
// u32 token-pair words. 16 waves, 1 block/CU; T5 setprio on MFMA cluster.
// ---------------------------------------------------------------------------
#define KPITCH 36
#define VPITCH 404                         // u32 words per d-row
#define KS_SZ  (LWIN * KPITCH)             // 28224 shorts = 56448 B
#define ATTN_LDS (KS_SZ * 2 + 32 * VPITCH * 4)   // 108160 bytes

__global__ __launch_bounds__(1024, 1) void k_attn_mfma(
    const unsigned short* __restrict__ qkv,   // (25088, 768) bf16
    unsigned short* __restrict__ ao)          // (25088, 256) bf16
{
    extern __shared__ unsigned short sm[];
    unsigned short* Ks = sm;                           // [784][36]
    unsigned int*   Vt = (unsigned int*)(sm + KS_SZ);  // [32][404]
    const int t = threadIdx.x;
    const int lane = t & 63, wave = t >> 6;
    const int lq = lane & 15, g = lane >> 4;
    const int h = blockIdx.x & 7, w = blockIdx.x >> 3;
    const size_t rowbase = (size_t)w * LWIN;
    const unsigned short* base = qkv + rowbase * QKVD;

    // ---- stage K: [784][36] ----
    for (int idx = t; idx < LWIN * 4; idx += 1024) {
        const int row = idx >> 2, c = idx & 3;
        uint4 kv = *(const uint4*)(base + (size_t)row * QKVD + 256 + h * 32 + c * 8);
        *(uint4*)(Ks + row * KPITCH + c * 8) = kv;
    }
    // ---- stage V: permuted-position packed token-pairs ----
    {
        const int c = t >> 8;          // d-octet 0..3
        const int p0 = t & 255;
        for (int tp = p0; tp < 392; tp += 256) {
            const int u = tp >> 4, tpp = tp & 15;
            const int a = tpp >> 3, gg = (tpp >> 1) & 3, rp = tpp & 1;
            const int wrd = u * 16 + gg * 4 + a * 2 + rp;
            union { uint4 u4; unsigned short s[8]; } x0, x1;
            x0.u4 = *(const uint4*)(base + (size_t)(2 * tp) * QKVD + 512 + h * 32 + c * 8);
            x1.u4 = *(const uint4*)(base + (size_t)(2 * tp + 1) * QKVD + 512 + h * 32 + c * 8);
#pragma unroll
            for (int j = 0; j < 8; ++j)
                Vt[(c * 8 + j) * VPITCH + wrd] =
                    (unsigned int)x0.s[j] | ((unsigned int)x1.s[j] << 16);
        }
    }
    // zero block-24's a=1 words (positions for the missing s=49 tile)
    for (int idx = t; idx < 32 * 8; idx += 1024) {
        const int d = idx >> 3, q = idx & 7;
        Vt[d * VPITCH + 384 + (q >> 1) * 4 + 2 + (q & 1)] = 0;
    }
    __syncthreads();

    // ---- per-wave q-tiles: wave 0 -> {0..3}, wave w -> {3w+1..3w+3} ----
    const int ntile = (wave == 0) ? 4 : 3;
    const int tbase = (wave == 0) ? 0 : (3 * wave + 1);

    short8v qf[4];
#pragma unroll
    for (int n = 0; n < 4; ++n)
        if (n < ntile)
            qf[n] = *(const short8v*)(base +
                    (size_t)((tbase + n) * 16 + lq) * QKVD + h * 32 + g * 8);

    floatx4 oa[4][2];
#pragma unroll
    for (int n = 0; n < 4; ++n) {
        oa[n][0] = (floatx4){0.f, 0.f, 0.f, 0.f};
        oa[n][1] = (floatx4){0.f, 0.f, 0.f, 0.f};
    }
    float lsum[4] = {0.f, 0.f, 0.f, 0.f};

    for (int u = 0; u < 25; ++u) {
        unsigned int pw[4][4];
        __builtin_amdgcn_s_setprio(1);
        {   // s = 2u
            short8v kf = *(const short8v*)(Ks + (size_t)(2 * u * 16 + lq) * KPITCH + g * 8);
#pragma unroll
            for (int n = 0; n < 4; ++n) if (n < ntile) {
                floatx4 st = __builtin_amdgcn_mfma_f32_16x16x32_bf16(
                    kf, qf[n], (floatx4){0.f, 0.f, 0.f, 0.f}, 0, 0, 0);
                float p0 = __builtin_amdgcn_exp2f(st[0]);
                float p1 = __builtin_amdgcn_exp2f(st[1]);
                float p2 = __builtin_amdgcn_exp2f(st[2]);
                float p3 = __builtin_amdgcn_exp2f(st[3]);
                lsum[n] += (p0 + p1) + (p2 + p3);
                pw[n][0] = cvt_pk_bf16(p0, p1);
                pw[n][1] = cvt_pk_bf16(p2, p3);
            }
        }
        if (u < 24) {   // s = 2u+1
            short8v kf = *(const short8v*)(Ks + (size_t)((2 * u + 1) * 16 + lq) * KPITCH + g * 8);
#pragma unroll
            for (int n = 0; n < 4; ++n) if (n < ntile) {
                floatx4 st = __builtin_amdgcn_mfma_f32_16x16x32_bf16(
                    kf, qf[n], (floatx4){0.f, 0.f, 0.f, 0.f}, 0, 0, 0);
                float p0 = __builtin_amdgcn_exp2f(st[0]);
                float p1 = __builtin_amdgcn_exp2f(st[1]);
                float p2 = __builtin_amdgcn_exp2f(st[2]);
                float p3 = __builtin_amdgcn_exp2f(st[3]);
                lsum[n] += (p0 + p1) + (p2 + p3);
                pw[n][2] = cvt_pk_bf16(p0, p1);
                pw[n][3] = cvt_pk_bf16(p2, p3);
            }
        } else {
#pragma unroll
            for (int n = 0; n < 4; ++n) if (n < ntile) {
                pw[n][2] = 0u; pw[n][3] = 0u;
            }
        }
        // ---- PV: A-frag = own pw words (permuted k-order), B = V from LDS ----
        const unsigned short* vrow0 = (const unsigned short*)Vt;
        short8v v0 = *(const short8v*)(vrow0 + (size_t)lq * (VPITCH * 2) + u * 32 + g * 8);
        short8v v1 = *(const short8v*)(vrow0 + (size_t)(lq + 16) * (VPITCH * 2) + u * 32 + g * 8);
#pragma unroll
        for (int n = 0; n < 4; ++n) if (n < ntile) {
            union { unsigned int wd[4]; short8v v; } pu;
            pu.wd[0] = pw[n][0]; pu.wd[1] = pw[n][1];
            pu.wd[2] = pw[n][2]; pu.wd[3] = pw[n][3];
            oa[n][0] = __builtin_amdgcn_mfma_f32_16x16x32_bf16(pu.v, v0, oa[n][0], 0, 0, 0);
            oa[n][1] = __builtin_amdgcn_mfma_f32_16x16x32_bf16(pu.v, v1, oa[n][1], 0, 0, 0);
        }
        __builtin_amdgcn_s_setprio(0);
    }

    // ---- normalize + store ----
#pragma unroll
    for (int n = 0; n < 4; ++n) if (n < ntile) {
        float l = lsum[n];
        l += __shfl_xor(l, 16);
        l += __shfl_xor(l, 32);
        float inv = 1.f / l;
        const size_t orow0 = rowbase + (size_t)(tbase + n) * 16;
#pragma unroll
        for (int r = 0; r < 4; ++r) {
            float ir = __shfl(inv, (lane & 48) | (g * 4 + r));
            size_t ob = (orow0 + g * 4 + r) * CDIM + h * 32;
            ao[ob + lq]      = f2bf(oa[n][0][r] * ir);
            ao[ob + 16 + lq] = f2bf(oa[n][1][r] * ir);
        }
    }
}

extern "C" void kernel_launch(void* const* d_in, const int* in_sizes, int n_in,
                              void* d_out, int out_size, void* d_ws, size_t ws_size,
                              hipStream_t stream) {
    const float* x      = (const float*)d_in[0];
    const float* qkv_w  = (const float*)d_in[1];
    const float* proj_w = (const float*)d_in[2];
    const float* proj_b = (const float*)d_in[3];
    float* out = (float*)d_out;

    unsigned short* qkvb = (unsigned short*)d_ws;
    unsigned short* xb   = qkvb + (size_t)M_ROWS * QKVD;
    unsigned short* aob  = xb;  // alias: xb dead once GEMM1 completes
    unsigned short* wqb  = xb + (size_t)M_ROWS * CDIM;
    unsigned short* wpb  = wqb + (size_t)QKVD * CDIM;

    hipFuncSetAttribute((const void*)k_attn_mfma,
                        hipFuncAttributeMaxDynamicSharedMemorySize, ATTN_LDS);

    k_f2bf3<<<2048, 256, 0, stream>>>(x, qkv_w, proj_w, xb, wqb, wpb);

    // GEMM1: grid = 6 * 196 = 1176 (8 | 1176)
    k_gemm_mfma<unsigned short, false, true>
        <<<(QKVD / 128) * (M_ROWS / 128), 256, 0, stream>>>(
            xb, wqb, nullptr, qkvb, QKVD, QKVD / 128);

    k_attn_mfma<<<dim3(NWINH), 1024, ATTN_LDS, stream>>>(qkvb, aob);

    // GEMM2: grid = 2 * 196 = 392 (8 | 392)
    k_gemm_mfma<float, true, false>
        <<<(CDIM / 128) * (M_ROWS / 128), 256, 0, stream>>>(
            aob, wpb, proj_b, out, CDIM, CDIM / 128);
}

// Round 19
// 80.544 us; speedup vs baseline: 4.3603x; 1.0045x over previous
//
#include <hip/hip_runtime.h>
#include <hip/hip_bf16.h>

// Problem constants (B=2, H=W=112, C=256, NHEAD=8, STRIP=7)
#define M_ROWS 25088
#define CDIM   256
#define QKVD   768
#define LWIN   784
#define NWINH  256   // 32 windows * 8 heads

typedef __attribute__((ext_vector_type(8))) short short8v;
typedef __attribute__((ext_vector_type(4))) float floatx4;

// scale * log2(e) = (1/sqrt(32)) * 1.4426950408889634
#define CEQ 0.2550660106245232f

static __device__ __forceinline__ unsigned short f2bf(float f) {
    unsigned int x = __float_as_uint(f);
    x += 0x7fffu + ((x >> 16) & 1u);
    return (unsigned short)(x >> 16);
}
static __device__ __forceinline__ unsigned int cvt_pk_bf16(float a, float b) {
    unsigned int r;
    asm("v_cvt_pk_bf16_f32 %0, %1, %2" : "=v"(r) : "v"(a), "v"(b));
    return r;  // lo16 = bf16(a), hi16 = bf16(b)
}
static __device__ __forceinline__ void gld_lds16(const unsigned short* g,
                                                 unsigned short* l) {
    __builtin_amdgcn_global_load_lds(
        (const __attribute__((address_space(1))) unsigned int*)g,
        (__attribute__((address_space(3))) unsigned int*)l, 16, 0, 0);
}

// ---------------------------------------------------------------------------
// Kernel 0: fp32 -> bf16 pack, all three tensors in ONE launch. [R11 verbatim]
// ---------------------------------------------------------------------------
#define N8_TOTAL ((M_ROWS * CDIM + QKVD * CDIM + CDIM * CDIM) / 8)

__global__ __launch_bounds__(256) void k_f2bf3(
    const float* __restrict__ s0,   // x       (M_ROWS*CDIM)
    const float* __restrict__ s1,   // qkv_w   (QKVD*CDIM)
    const float* __restrict__ s2,   // proj_w  (CDIM*CDIM)
    unsigned short* __restrict__ d0,
    unsigned short* __restrict__ d1,
    unsigned short* __restrict__ d2)
{
    const int n80 = (M_ROWS * CDIM) / 8;
    const int n81 = (QKVD * CDIM) / 8;
    for (int i = blockIdx.x * 256 + threadIdx.x; i < N8_TOTAL;
         i += gridDim.x * 256) {
        const float4* s4;
        uint4* d4;
        int j = i;
        if (j < n80)            { s4 = (const float4*)s0; d4 = (uint4*)d0; }
        else if ((j -= n80) < n81) { s4 = (const float4*)s1; d4 = (uint4*)d1; }
        else                    { j -= n81; s4 = (const float4*)s2; d4 = (uint4*)d2; }
        float4 a = s4[2 * j], b = s4[2 * j + 1];
        uint4 o;
        o.x = cvt_pk_bf16(a.x, a.y);
        o.y = cvt_pk_bf16(a.z, a.w);
        o.z = cvt_pk_bf16(b.x, b.y);
        o.w = cvt_pk_bf16(b.z, b.w);
        d4[j] = o;
    }
}

// ---------------------------------------------------------------------------
// Kernel 1/3: C(M,N) = A(M,256) @ B(N,256)^T [+ bias], bf16 MFMA.
// [R11 staging/compute verbatim] + T1 bijective XCD swizzle: 1D grid
// (nwg % 8 == 0), swz = (lin&7)*(nwg/8) + (lin>>3) -> each XCD covers
// contiguous row-panels across all col-tiles, so A-panel re-reads L2-hit.
// ---------------------------------------------------------------------------
template <typename OUT_T, bool BIAS, bool SCALEQ>
__global__ __launch_bounds__(256, 2) void k_gemm_mfma(
    const unsigned short* __restrict__ A,   // (M, 256) bf16
    const unsigned short* __restrict__ B,   // (N, 256) bf16
    const float* __restrict__ bias,         // (N) or nullptr
    OUT_T* __restrict__ Y, int N, int nbx)  // (M, N); nbx = N/128
{
    __shared__ __attribute__((aligned(16))) unsigned short As[128 * 64];
    __shared__ __attribute__((aligned(16))) unsigned short Bs[128 * 64];
    const int t = threadIdx.x;
    const int lane = t & 63, wv = t >> 6;
    const int lq = lane & 15, g = lane >> 4;
    const int wm = wv >> 1, wn = wv & 1;
    const int lin = blockIdx.x;
    const int swz = (lin & 7) * (gridDim.x >> 3) + (lin >> 3);
    const int R0 = (swz / nbx) * 128, C0 = (swz % nbx) * 128;
    const int lrow = t >> 3, lch = (t & 7) * 8;

    floatx4 acc[4][4];
#pragma unroll
    for (int i = 0; i < 4; ++i)
#pragma unroll
        for (int j = 0; j < 4; ++j) acc[i][j] = (floatx4){0.f, 0.f, 0.f, 0.f};

    for (int kc = 0; kc < 256; kc += 64) {
#pragma unroll
        for (int i = 0; i < 4; ++i) {
            gld_lds16(A + (size_t)(R0 + i * 32 + lrow) * 256 + kc + lch,
                      As + (i * 32 + wv * 8) * 64);
            gld_lds16(B + (size_t)(C0 + i * 32 + lrow) * 256 + kc + lch,
                      Bs + (i * 32 + wv * 8) * 64);
        }
        __syncthreads();
#pragma unroll
        for (int kk = 0; kk < 64; kk += 32) {
            short8v af[4], bf[4];
#pragma unroll
            for (int mi = 0; mi < 4; ++mi)
                af[mi] = *(const short8v*)(As + (wm * 64 + mi * 16 + lq) * 64 +
                                           kk + g * 8);
#pragma unroll
            for (int ni = 0; ni < 4; ++ni)
                bf[ni] = *(const short8v*)(Bs + (wn * 64 + ni * 16 + lq) * 64 +
                                           kk + g * 8);
#pragma unroll
            for (int mi = 0; mi < 4; ++mi)
#pragma unroll
                for (int ni = 0; ni < 4; ++ni)
                    acc[mi][ni] = __builtin_amdgcn_mfma_f32_16x16x32_bf16(
                        af[mi], bf[ni], acc[mi][ni], 0, 0, 0);
        }
        __syncthreads();
    }

#pragma unroll
    for (int mi = 0; mi < 4; ++mi) {
        const size_t rb = (size_t)R0 + wm * 64 + mi * 16 + g * 4;
#pragma unroll
        for (int ni = 0; ni < 4; ++ni) {
            const int col = C0 + wn * 64 + ni * 16 + lq;
            float bv = 0.f;
            if constexpr (BIAS) bv = bias[col];
#pragma unroll
            for (int r = 0; r < 4; ++r) {
                float val = acc[mi][ni][r];
                if constexpr (SCALEQ) { if (col < 256) val *= CEQ; }
                val += bv;
                if constexpr (sizeof(OUT_T) == 2)
                    Y[(rb + r) * N + col] = (OUT_T)f2bf(val);
                else
                    Y[(rb + r) * N + col] = (OUT_T)val;
            }
        }
    }
}

// ---------------------------------------------------------------------------
// Kernel 2: MFMA attention — R11 VERBATIM (verified 45.2us). The u-loop is
// FROZEN: four independent restructuring attempts (R7/R8 3-phase, R16
// unroll-2, R18 load-rotation) failed in four different modes; this exact
// loop body is the only verified-correct form.
// Register-P via permuted k-order (pos 8g+j <-> token (j>=4?16:0)+4g+(j&3));
// V staged with matching permutation. K: [784][36] shorts. V: [32][404]
// u32 token-pair words. 16 waves, 1 block/CU; T5 setprio on MFMA cluster.
// ---------------------------------------------------------------------------
#define KPITCH 36
#define VPITCH 404                         // u32 words per d-row
#define KS_SZ  (LWIN * KPITCH)             // 28224 shorts = 56448 B
#define ATTN_LDS (KS_SZ * 2 + 32 * VPITCH * 4)   // 108160 bytes

__global__ __launch_bounds__(1024, 1) void k_attn_mfma(
    const unsigned short* __restrict__ qkv,   // (25088, 768) bf16
    unsigned short* __restrict__ ao)          // (25088, 256) bf16
{
    extern __shared__ unsigned short sm[];
    unsigned short* Ks = sm;                           // [784][36]
    unsigned int*   Vt = (unsigned int*)(sm + KS_SZ);  // [32][404]
    const int t = threadIdx.x;
    const int lane = t & 63, wave = t >> 6;
    const int lq = lane & 15, g = lane >> 4;
    const int h = blockIdx.x & 7, w = blockIdx.x >> 3;
    const size_t rowbase = (size_t)w * LWIN;
    const unsigned short* base = qkv + rowbase * QKVD;

    // ---- stage K: [784][36] ----
    for (int idx = t; idx < LWIN * 4; idx += 1024) {
        const int row = idx >> 2, c = idx & 3;
        uint4 kv = *(const uint4*)(base + (size_t)row * QKVD + 256 + h * 32 + c * 8);
        *(uint4*)(Ks + row * KPITCH + c * 8) = kv;
    }
    // ---- stage V: permuted-position packed token-pairs ----
    {
        const int c = t >> 8;          // d-octet 0..3
        const int p0 = t & 255;
        for (int tp = p0; tp < 392; tp += 256) {
            const int u = tp >> 4, tpp = tp & 15;
            const int a = tpp >> 3, gg = (tpp >> 1) & 3, rp = tpp & 1;
            const int wrd = u * 16 + gg * 4 + a * 2 + rp;
            union { uint4 u4; unsigned short s[8]; } x0, x1;
            x0.u4 = *(const uint4*)(base + (size_t)(2 * tp) * QKVD + 512 + h * 32 + c * 8);
            x1.u4 = *(const uint4*)(base + (size_t)(2 * tp + 1) * QKVD + 512 + h * 32 + c * 8);
#pragma unroll
            for (int j = 0; j < 8; ++j)
                Vt[(c * 8 + j) * VPITCH + wrd] =
                    (unsigned int)x0.s[j] | ((unsigned int)x1.s[j] << 16);
        }
    }
    // zero block-24's a=1 words (positions for the missing s=49 tile)
    for (int idx = t; idx < 32 * 8; idx += 1024) {
        const int d = idx >> 3, q = idx & 7;
        Vt[d * VPITCH + 384 + (q >> 1) * 4 + 2 + (q & 1)] = 0;
    }
    __syncthreads();

    // ---- per-wave q-tiles: wave 0 -> {0..3}, wave w -> {3w+1..3w+3} ----
    const int ntile = (wave == 0) ? 4 : 3;
    const int tbase = (wave == 0) ? 0 : (3 * wave + 1);

    short8v qf[4];
#pragma unroll
    for (int n = 0; n < 4; ++n)
        if (n < ntile)
            qf[n] = *(const short8v*)(base +
                    (size_t)((tbase + n) * 16 + lq) * QKVD + h * 32 + g * 8);

    floatx4 oa[4][2];
#pragma unroll
    for (int n = 0; n < 4; ++n) {
        oa[n][0] = (floatx4){0.f, 0.f, 0.f, 0.f};
        oa[n][1] = (floatx4){0.f, 0.f, 0.f, 0.f};
    }
    float lsum[4] = {0.f, 0.f, 0.f, 0.f};

    for (int u = 0; u < 25; ++u) {
        unsigned int pw[4][4];
        __builtin_amdgcn_s_setprio(1);
        {   // s = 2u
            short8v kf = *(const short8v*)(Ks + (size_t)(2 * u * 16 + lq) * KPITCH + g * 8);
#pragma unroll
            for (int n = 0; n < 4; ++n) if (n < ntile) {
                floatx4 st = __builtin_amdgcn_mfma_f32_16x16x32_bf16(
                    kf, qf[n], (floatx4){0.f, 0.f, 0.f, 0.f}, 0, 0, 0);
                float p0 = __builtin_amdgcn_exp2f(st[0]);
                float p1 = __builtin_amdgcn_exp2f(st[1]);
                float p2 = __builtin_amdgcn_exp2f(st[2]);
                float p3 = __builtin_amdgcn_exp2f(st[3]);
                lsum[n] += (p0 + p1) + (p2 + p3);
                pw[n][0] = cvt_pk_bf16(p0, p1);
                pw[n][1] = cvt_pk_bf16(p2, p3);
            }
        }
        if (u < 24) {   // s = 2u+1
            short8v kf = *(const short8v*)(Ks + (size_t)((2 * u + 1) * 16 + lq) * KPITCH + g * 8);
#pragma unroll
            for (int n = 0; n < 4; ++n) if (n < ntile) {
                floatx4 st = __builtin_amdgcn_mfma_f32_16x16x32_bf16(
                    kf, qf[n], (floatx4){0.f, 0.f, 0.f, 0.f}, 0, 0, 0);
                float p0 = __builtin_amdgcn_exp2f(st[0]);
                float p1 = __builtin_amdgcn_exp2f(st[1]);
                float p2 = __builtin_amdgcn_exp2f(st[2]);
                float p3 = __builtin_amdgcn_exp2f(st[3]);
                lsum[n] += (p0 + p1) + (p2 + p3);
                pw[n][2] = cvt_pk_bf16(p0, p1);
                pw[n][3] = cvt_pk_bf16(p2, p3);
            }
        } else {
#pragma unroll
            for (int n = 0; n < 4; ++n) if (n < ntile) {
                pw[n][2] = 0u; pw[n][3] = 0u;
            }
        }
        // ---- PV: A-frag = own pw words (permuted k-order), B = V from LDS ----
        const unsigned short* vrow0 = (const unsigned short*)Vt;
        short8v v0 = *(const short8v*)(vrow0 + (size_t)lq * (VPITCH * 2) + u * 32 + g * 8);
        short8v v1 = *(const short8v*)(vrow0 + (size_t)(lq + 16) * (VPITCH * 2) + u * 32 + g * 8);
#pragma unroll
        for (int n = 0; n < 4; ++n) if (n < ntile) {
            union { unsigned int wd[4]; short8v v; } pu;
            pu.wd[0] = pw[n][0]; pu.wd[1] = pw[n][1];
            pu.wd[2] = pw[n][2]; pu.wd[3] = pw[n][3];
            oa[n][0] = __builtin_amdgcn_mfma_f32_16x16x32_bf16(pu.v, v0, oa[n][0], 0, 0, 0);
            oa[n][1] = __builtin_amdgcn_mfma_f32_16x16x32_bf16(pu.v, v1, oa[n][1], 0, 0, 0);
        }
        __builtin_amdgcn_s_setprio(0);
    }

    // ---- normalize + store ----
#pragma unroll
    for (int n = 0; n < 4; ++n) if (n < ntile) {
        float l = lsum[n];
        l += __shfl_xor(l, 16);
        l += __shfl_xor(l, 32);
        float inv = 1.f / l;
        const size_t orow0 = rowbase + (size_t)(tbase + n) * 16;
#pragma unroll
        for (int r = 0; r < 4; ++r) {
            float ir = __shfl(inv, (lane & 48) | (g * 4 + r));
            size_t ob = (orow0 + g * 4 + r) * CDIM + h * 32;
            ao[ob + lq]      = f2bf(oa[n][0][r] * ir);
            ao[ob + 16 + lq] = f2bf(oa[n][1][r] * ir);
        }
    }
}

extern "C" void kernel_launch(void* const* d_in, const int* in_sizes, int n_in,
                              void* d_out, int out_size, void* d_ws, size_t ws_size,
                              hipStream_t stream) {
    const float* x      = (const float*)d_in[0];
    const float* qkv_w  = (const float*)d_in[1];
    const float* proj_w = (const float*)d_in[2];
    const float* proj_b = (const float*)d_in[3];
    float* out = (float*)d_out;

    unsigned short* qkvb = (unsigned short*)d_ws;
    unsigned short* xb   = qkvb + (size_t)M_ROWS * QKVD;
    unsigned short* aob  = xb;  // alias: xb dead once GEMM1 completes
    unsigned short* wqb  = xb + (size_t)M_ROWS * CDIM;
    unsigned short* wpb  = wqb + (size_t)QKVD * CDIM;

    hipFuncSetAttribute((const void*)k_attn_mfma,
                        hipFuncAttributeMaxDynamicSharedMemorySize, ATTN_LDS);

    k_f2bf3<<<2048, 256, 0, stream>>>(x, qkv_w, proj_w, xb, wqb, wpb);

    // GEMM1: grid = 6 * 196 = 1176 (8 | 1176)
    k_gemm_mfma<unsigned short, false, true>
        <<<(QKVD / 128) * (M_ROWS / 128), 256, 0, stream>>>(
            xb, wqb, nullptr, qkvb, QKVD, QKVD / 128);

    k_attn_mfma<<<dim3(NWINH), 1024, ATTN_LDS, stream>>>(qkvb, aob);

    // GEMM2: grid = 2 * 196 = 392 (8 | 392)
    k_gemm_mfma<float, true, false>
        <<<(CDIM / 128) * (M_ROWS / 128), 256, 0, stream>>>(
            aob, wpb, proj_b, out, CDIM, CDIM / 128);
}